// Round 1
// baseline (6431.672 us; speedup 1.0000x reference)
//
#include <hip/hip_runtime.h>
#include <cstdint>
#include <cstddef>

#define N_NODES 100000
#define M_EDGES 20000
#define P_PAIRS 1600000
#define CIN 768
#define HID 128
#define OUT_C 16
#define NLAYERS 16
#define LN_EPS 1e-5f

// ------------------------- CSR build -------------------------

__global__ void hist_kernel(const int* __restrict__ v_idx, const int* __restrict__ e_idx,
                            unsigned* __restrict__ cnt_v, unsigned* __restrict__ cnt_e) {
    int p = blockIdx.x * 256 + threadIdx.x;
    if (p < P_PAIRS) {
        atomicAdd(&cnt_v[v_idx[p]], 1u);
        atomicAdd(&cnt_e[e_idx[p]], 1u);
    }
}

// single-block exclusive scan; also emits a mutable cursor copy and 1/max(cnt,1)
__global__ void scan_kernel(const unsigned* __restrict__ cnt, int n,
                            unsigned* __restrict__ offs, unsigned* __restrict__ cur,
                            float* __restrict__ inv) {
    __shared__ unsigned sdata[1024];
    __shared__ unsigned carry;
    int tid = threadIdx.x;
    if (tid == 0) carry = 0u;
    __syncthreads();
    for (int base = 0; base < n; base += 1024) {
        int i = base + tid;
        unsigned v = (i < n) ? cnt[i] : 0u;
        if (i < n) inv[i] = 1.0f / (float)(v > 1u ? v : 1u);
        sdata[tid] = v;
        __syncthreads();
        for (int off = 1; off < 1024; off <<= 1) {
            unsigned t = (tid >= off) ? sdata[tid - off] : 0u;
            __syncthreads();
            sdata[tid] += t;
            __syncthreads();
        }
        unsigned excl = sdata[tid] - v;
        unsigned c = carry;
        if (i < n) { offs[i] = c + excl; cur[i] = c + excl; }
        __syncthreads();
        if (tid == 1023) carry = c + sdata[1023];
        __syncthreads();
    }
    if (tid == 0) offs[n] = carry;
}

__global__ void fill_kernel(const int* __restrict__ v_idx, const int* __restrict__ e_idx,
                            unsigned* __restrict__ cur_v, unsigned* __restrict__ cur_e,
                            int* __restrict__ vert_nbr, int* __restrict__ edge_nbr) {
    int p = blockIdx.x * 256 + threadIdx.x;
    if (p < P_PAIRS) {
        int v = v_idx[p], e = e_idx[p];
        unsigned sv = atomicAdd(&cur_v[v], 1u);
        vert_nbr[sv] = e;                        // per-vertex list stores edge ids
        unsigned se = atomicAdd(&cur_e[e], 1u);
        edge_nbr[se] = v;                        // per-edge list stores vertex ids
    }
}

// ------------------------- GEMM (fp32, tiled) -------------------------
// out[n,128] = A[n,K] @ W[K,128] + bias ; optional zero-mask where cnt[row]==0

__global__ __launch_bounds__(256) void gemm_bias_kernel(
    const float* __restrict__ A, const float* __restrict__ W,
    const float* __restrict__ bias, float* __restrict__ out,
    int n, int K, const unsigned* __restrict__ cnt) {
    __shared__ float Xs[64][65];
    __shared__ float Ws[64][128];
    int tid = threadIdx.x;
    int row0 = blockIdx.x * 64;
    int ty = tid >> 4, tx = tid & 15;
    float acc[4][8];
#pragma unroll
    for (int r = 0; r < 4; r++)
#pragma unroll
        for (int c = 0; c < 8; c++) acc[r][c] = 0.f;

    for (int k0 = 0; k0 < K; k0 += 64) {
#pragma unroll
        for (int i = 0; i < 16; i++) {
            int idx = tid + i * 256;             // 0..4095
            int r = idx >> 6, k = idx & 63;
            int row = row0 + r;
            Xs[r][k] = (row < n) ? A[(size_t)row * K + k0 + k] : 0.f;
        }
        const float4* W4 = (const float4*)W;
#pragma unroll
        for (int i = 0; i < 8; i++) {
            int idx = tid + i * 256;             // 0..2047 float4s
            int kk = idx >> 5, c4 = idx & 31;
            ((float4*)Ws[kk])[c4] = W4[(size_t)(k0 + kk) * 32 + c4];
        }
        __syncthreads();
#pragma unroll
        for (int k = 0; k < 64; k++) {
            float xv[4];
#pragma unroll
            for (int r = 0; r < 4; r++) xv[r] = Xs[ty * 4 + r][k];
            float4 wa = *(const float4*)&Ws[k][tx * 4];
            float4 wb = *(const float4*)&Ws[k][64 + tx * 4];
            float wv[8] = {wa.x, wa.y, wa.z, wa.w, wb.x, wb.y, wb.z, wb.w};
#pragma unroll
            for (int r = 0; r < 4; r++)
#pragma unroll
                for (int c = 0; c < 8; c++) acc[r][c] += xv[r] * wv[c];
        }
        __syncthreads();
    }
#pragma unroll
    for (int r = 0; r < 4; r++) {
        int row = row0 + ty * 4 + r;
        if (row >= n) continue;
        bool zero = (cnt != nullptr) && (cnt[row] == 0u);
        float4 o1, o2;
        o1.x = zero ? 0.f : acc[r][0] + bias[tx * 4 + 0];
        o1.y = zero ? 0.f : acc[r][1] + bias[tx * 4 + 1];
        o1.z = zero ? 0.f : acc[r][2] + bias[tx * 4 + 2];
        o1.w = zero ? 0.f : acc[r][3] + bias[tx * 4 + 3];
        o2.x = zero ? 0.f : acc[r][4] + bias[64 + tx * 4 + 0];
        o2.y = zero ? 0.f : acc[r][5] + bias[64 + tx * 4 + 1];
        o2.z = zero ? 0.f : acc[r][6] + bias[64 + tx * 4 + 2];
        o2.w = zero ? 0.f : acc[r][7] + bias[64 + tx * 4 + 3];
        *(float4*)&out[(size_t)row * HID + tx * 4] = o1;
        *(float4*)&out[(size_t)row * HID + 64 + tx * 4] = o2;
    }
}

// ------------------------- LayerNorm + ReLU -------------------------
// one wave per row; lane owns channels (lane, lane+64)

__global__ __launch_bounds__(256) void ln_relu_kernel(const float* __restrict__ x,
                                                      const float* __restrict__ g,
                                                      const float* __restrict__ b,
                                                      float* __restrict__ a) {
    int row = (blockIdx.x * 256 + threadIdx.x) >> 6;
    int lane = threadIdx.x & 63;
    if (row >= N_NODES) return;
    const float* xr = x + (size_t)row * HID;
    float v0 = xr[lane], v1 = xr[lane + 64];
    float s = v0 + v1;
#pragma unroll
    for (int off = 1; off < 64; off <<= 1) s += __shfl_xor(s, off);
    float mu = s * (1.0f / 128.0f);
    float d0 = v0 - mu, d1 = v1 - mu;
    float q = d0 * d0 + d1 * d1;
#pragma unroll
    for (int off = 1; off < 64; off <<= 1) q += __shfl_xor(q, off);
    float rstd = rsqrtf(q * (1.0f / 128.0f) + LN_EPS);
    float h0 = d0 * rstd * g[lane] + b[lane];
    float h1 = d1 * rstd * g[lane + 64] + b[lane + 64];
    float* ar = a + (size_t)row * HID;
    ar[lane] = h0 > 0.f ? h0 : 0.f;
    ar[lane + 64] = h1 > 0.f ? h1 : 0.f;
}

// ------------------------- edge aggregation -------------------------
// Ae[m] = inv_ce[m] * sum_{v in edge m} a[v]  ; block(128) per edge, thread=channel

__global__ __launch_bounds__(128) void edge_agg_kernel(const float* __restrict__ a,
                                                       const int* __restrict__ edge_nbr,
                                                       const unsigned* __restrict__ offs,
                                                       const float* __restrict__ inv_ce,
                                                       float* __restrict__ Ae) {
    __shared__ int nbrs[128];
    int m = blockIdx.x;
    int t = threadIdx.x;
    unsigned beg = offs[m], end = offs[m + 1];
    int deg = (int)(end - beg);
    float sum = 0.f;
    for (int j0 = 0; j0 < deg; j0 += 128) {
        __syncthreads();
        if (j0 + t < deg) nbrs[t] = edge_nbr[beg + j0 + t];
        __syncthreads();
        int lim = min(128, deg - j0);
        for (int k = 0; k < lim; k++) {
            int v = nbrs[k];
            sum += a[(size_t)v * HID + t];
        }
    }
    Ae[(size_t)m * HID + t] = sum * inv_ce[m];
}

// ------------------------- vertex aggregation + residual -------------------------
// x[v] += relu(inv_cv[v] * sum_{e ∋ v} Xe[e]) ; one wave per vertex

__global__ __launch_bounds__(256) void vert_agg_kernel(const float* __restrict__ Xe,
                                                       const int* __restrict__ vert_nbr,
                                                       const unsigned* __restrict__ offs,
                                                       const float* __restrict__ inv_cv,
                                                       float* __restrict__ x) {
    int v = (blockIdx.x * 256 + threadIdx.x) >> 6;
    int lane = threadIdx.x & 63;
    if (v >= N_NODES) return;
    unsigned beg = offs[v], end = offs[v + 1];
    float s0 = 0.f, s1 = 0.f;
    for (unsigned j = beg; j < end; j++) {
        int e = vert_nbr[j];
        const float* xr = Xe + (size_t)e * HID;
        s0 += xr[lane];
        s1 += xr[lane + 64];
    }
    float ic = inv_cv[v];
    float y0 = s0 * ic, y1 = s1 * ic;
    y0 = y0 > 0.f ? y0 : 0.f;
    y1 = y1 > 0.f ? y1 : 0.f;
    float* xp = x + (size_t)v * HID;
    xp[lane] += y0;
    xp[lane + 64] += y1;
}

// ------------------------- head: x @ W_out + b_out, log_softmax -------------------------
// block 256 = 4 waves; wave handles 4 rows; lane: r=lane/16, c=lane%16

__global__ __launch_bounds__(256) void out_kernel(const float* __restrict__ x,
                                                  const float* __restrict__ Wo,
                                                  const float* __restrict__ bo,
                                                  float* __restrict__ out) {
    __shared__ float Ws[128][16];
    __shared__ float rowbuf[16][132];
    __shared__ float bsm[16];
    int tid = threadIdx.x;
#pragma unroll
    for (int i = 0; i < 8; i++) {
        int idx = tid + i * 256;                 // 0..2047
        ((float*)Ws)[idx] = Wo[idx];
    }
    if (tid < 16) bsm[tid] = bo[tid];
    int row0 = blockIdx.x * 16;
    int w = tid >> 6, lane = tid & 63;
#pragma unroll
    for (int i = 0; i < 8; i++) {
        int idx = lane + i * 64;                 // 0..511
        int r = idx >> 7, k = idx & 127;
        int row = row0 + w * 4 + r;
        rowbuf[w * 4 + r][k] = (row < N_NODES) ? x[(size_t)row * HID + k] : 0.f;
    }
    __syncthreads();
    int r = lane >> 4, c = lane & 15;
    int row = row0 + w * 4 + r;
    float acc = bsm[c];
#pragma unroll
    for (int k = 0; k < 128; k++) acc += rowbuf[w * 4 + r][k] * Ws[k][c];
    float mx = acc;
#pragma unroll
    for (int off = 1; off < 16; off <<= 1) mx = fmaxf(mx, __shfl_xor(mx, off));
    float e = expf(acc - mx);
    float s = e;
#pragma unroll
    for (int off = 1; off < 16; off <<= 1) s += __shfl_xor(s, off);
    float val = acc - mx - logf(s);
    if (row < N_NODES) out[(size_t)row * OUT_C + c] = val;
}

// ------------------------- launch -------------------------

extern "C" void kernel_launch(void* const* d_in, const int* in_sizes, int n_in,
                              void* d_out, int out_size, void* d_ws, size_t ws_size,
                              hipStream_t stream) {
    const float* X     = (const float*)d_in[0];
    const int*   v_idx = (const int*)d_in[1];
    const int*   e_idx = (const int*)d_in[2];
    const float* W_enc = (const float*)d_in[3];
    const float* b_enc = (const float*)d_in[4];
    const float* ln_g  = (const float*)d_in[5];
    const float* ln_b  = (const float*)d_in[6];
    const float* Wt    = (const float*)d_in[7];
    const float* bt    = (const float*)d_in[8];
    const float* W_out = (const float*)d_in[9];
    const float* b_out = (const float*)d_in[10];
    float* out = (float*)d_out;

    char* ws = (char*)d_ws;
    auto alloc = [&](size_t bytes) -> void* {
        void* p = (void*)ws;
        ws += (bytes + 255) & ~(size_t)255;
        return p;
    };
    float* x  = (float*)alloc((size_t)N_NODES * HID * 4);
    float* a  = (float*)alloc((size_t)N_NODES * HID * 4);
    float* Ae = (float*)alloc((size_t)M_EDGES * HID * 4);
    float* Xe = (float*)alloc((size_t)M_EDGES * HID * 4);
    int* edge_nbr = (int*)alloc((size_t)P_PAIRS * 4);
    int* vert_nbr = (int*)alloc((size_t)P_PAIRS * 4);
    unsigned* cnt_e = (unsigned*)alloc((size_t)(M_EDGES + N_NODES) * 4); // contiguous for one memset
    unsigned* cnt_v = cnt_e + M_EDGES;
    unsigned* offs_e = (unsigned*)alloc((size_t)(M_EDGES + 1) * 4);
    unsigned* offs_v = (unsigned*)alloc((size_t)(N_NODES + 1) * 4);
    unsigned* cur_e  = (unsigned*)alloc((size_t)M_EDGES * 4);
    unsigned* cur_v  = (unsigned*)alloc((size_t)N_NODES * 4);
    float* inv_ce = (float*)alloc((size_t)M_EDGES * 4);
    float* inv_cv = (float*)alloc((size_t)N_NODES * 4);

    // CSR build
    hipMemsetAsync(cnt_e, 0, (size_t)(M_EDGES + N_NODES) * 4, stream);
    hist_kernel<<<(P_PAIRS + 255) / 256, 256, 0, stream>>>(v_idx, e_idx, cnt_v, cnt_e);
    scan_kernel<<<1, 1024, 0, stream>>>(cnt_e, M_EDGES, offs_e, cur_e, inv_ce);
    scan_kernel<<<1, 1024, 0, stream>>>(cnt_v, N_NODES, offs_v, cur_v, inv_cv);
    fill_kernel<<<(P_PAIRS + 255) / 256, 256, 0, stream>>>(v_idx, e_idx, cur_v, cur_e,
                                                           vert_nbr, edge_nbr);

    // encoder: x = X @ W_enc + b_enc
    gemm_bias_kernel<<<(N_NODES + 63) / 64, 256, 0, stream>>>(X, W_enc, b_enc, x,
                                                              N_NODES, CIN, nullptr);

    // 16 layers
    for (int l = 0; l < NLAYERS; l++) {
        ln_relu_kernel<<<(N_NODES + 3) / 4, 256, 0, stream>>>(x, ln_g + l * HID,
                                                              ln_b + l * HID, a);
        edge_agg_kernel<<<M_EDGES, 128, 0, stream>>>(a, edge_nbr, offs_e, inv_ce, Ae);
        gemm_bias_kernel<<<(M_EDGES + 63) / 64, 256, 0, stream>>>(
            Ae, Wt + (size_t)l * HID * HID, bt + (size_t)l * HID, Xe, M_EDGES, HID, cnt_e);
        vert_agg_kernel<<<(N_NODES + 3) / 4, 256, 0, stream>>>(Xe, vert_nbr, offs_v,
                                                               inv_cv, x);
    }

    // head
    out_kernel<<<(N_NODES + 15) / 16, 256, 0, stream>>>(x, W_out, b_out, out);
}

// Round 2
// 4589.110 us; speedup vs baseline: 1.4015x; 1.4015x over previous
//
#include <hip/hip_runtime.h>
#include <cstdint>
#include <cstddef>

#define N_NODES 100000
#define M_EDGES 20000
#define P_PAIRS 1600000
#define CIN 768
#define HID 128
#define OUT_C 16
#define NLAYERS 16
#define LN_EPS 1e-5f

using half8  = __attribute__((ext_vector_type(8))) _Float16;
using half4v = __attribute__((ext_vector_type(4))) _Float16;
using half2v = __attribute__((ext_vector_type(2))) _Float16;
using f32x4  = __attribute__((ext_vector_type(4))) float;

// ------------------------- CSR build -------------------------

__global__ void hist_kernel(const int* __restrict__ v_idx, const int* __restrict__ e_idx,
                            unsigned* __restrict__ cnt_v, unsigned* __restrict__ cnt_e) {
    int p = blockIdx.x * 256 + threadIdx.x;
    if (p < P_PAIRS) {
        atomicAdd(&cnt_v[v_idx[p]], 1u);
        atomicAdd(&cnt_e[e_idx[p]], 1u);
    }
}

// single-block exclusive scan via wave shuffles; emits cursor copy and 1/max(cnt,1)
__global__ void scan_kernel(const unsigned* __restrict__ cnt, int n,
                            unsigned* __restrict__ offs, unsigned* __restrict__ cur,
                            float* __restrict__ inv) {
    __shared__ unsigned wsum[16];
    __shared__ unsigned carry_s;
    int tid = threadIdx.x;
    int lane = tid & 63, w = tid >> 6;   // 1024 threads = 16 waves
    if (tid == 0) carry_s = 0u;
    __syncthreads();
    for (int base = 0; base < n; base += 1024) {
        int i = base + tid;
        unsigned v = (i < n) ? cnt[i] : 0u;
        if (i < n) inv[i] = 1.0f / (float)(v > 1u ? v : 1u);
        unsigned s = v;
#pragma unroll
        for (int off = 1; off < 64; off <<= 1) {
            unsigned t = __shfl_up(s, off);
            if (lane >= off) s += t;
        }
        if (lane == 63) wsum[w] = s;
        __syncthreads();
        if (w == 0 && lane < 16) {
            unsigned ws = wsum[lane];
#pragma unroll
            for (int off = 1; off < 16; off <<= 1) {
                unsigned t = __shfl_up(ws, off);
                if (lane >= off) ws += t;
            }
            wsum[lane] = ws;            // inclusive over waves
        }
        __syncthreads();
        unsigned wexcl = (w == 0) ? 0u : wsum[w - 1];
        unsigned carry = carry_s;
        unsigned incl = carry + wexcl + s;
        unsigned excl = incl - v;
        if (i < n) { offs[i] = excl; cur[i] = excl; }
        __syncthreads();
        if (tid == 1023) carry_s = incl;  // last wave's lane63 holds chunk total
        __syncthreads();
    }
    if (tid == 0) offs[n] = carry_s;
}

__global__ void fill_kernel(const int* __restrict__ v_idx, const int* __restrict__ e_idx,
                            unsigned* __restrict__ cur_v, unsigned* __restrict__ cur_e,
                            int* __restrict__ vert_nbr, int* __restrict__ edge_nbr) {
    int p = blockIdx.x * 256 + threadIdx.x;
    if (p < P_PAIRS) {
        int v = v_idx[p], e = e_idx[p];
        unsigned sv = atomicAdd(&cur_v[v], 1u);
        vert_nbr[sv] = e;
        unsigned se = atomicAdd(&cur_e[e], 1u);
        edge_nbr[se] = v;
    }
}

// ------------------------- weight transpose+convert -------------------------
// src: [K x 128] fp32 row-major (per layer), dst: [128 x K] fp16 (k-contiguous)
__global__ void convert_wT_kernel(const float* __restrict__ W, _Float16* __restrict__ WT,
                                  int K) {
    const float* src = W + (size_t)blockIdx.y * K * 128;
    _Float16* dst = WT + (size_t)blockIdx.y * K * 128;
    int idx = blockIdx.x * 256 + threadIdx.x;
    if (idx < K * 128) {
        int k = idx >> 7, n = idx & 127;
        dst[(size_t)n * K + k] = (_Float16)src[idx];
    }
}

// ------------------------- MFMA GEMM -------------------------
// out[row, 0..127] = A[row, 0..K) @ B[K x 128] + bias
// Bt is [n=128][K] fp16, k-contiguous. Block: 256 thr, tile 128 rows x 128 cols.
// Wave (2x2 grid) computes 64x64 via 4x4 tiles of 16x16x32 MFMA.

#define BK  64
#define LDK 72   // padded LDS stride in halves (+8 -> bank-clean b128 frags)

template<bool A_FP32, bool OUT_HALF>
__global__ __launch_bounds__(256) void mfma_gemm_kernel(
    const void* __restrict__ Ap, const _Float16* __restrict__ Bt,
    const float* __restrict__ bias, void* __restrict__ outp,
    int nrows, int K) {
    __shared__ _Float16 Asm[128 * LDK];
    __shared__ _Float16 Bsm[128 * LDK];
    int tid = threadIdx.x;
    int row0 = blockIdx.x * 128;
    int lane = tid & 63, wave = tid >> 6;
    int wy = wave >> 1, wx = wave & 1;
    int m16 = lane & 15, quad = lane >> 4;

    f32x4 acc[4][4];
#pragma unroll
    for (int r = 0; r < 4; r++)
#pragma unroll
        for (int c = 0; c < 4; c++) acc[r][c] = (f32x4)0.f;

    float bv[4];
#pragma unroll
    for (int c = 0; c < 4; c++) bv[c] = bias[wx * 64 + c * 16 + m16];

    for (int k0 = 0; k0 < K; k0 += BK) {
        __syncthreads();
        if (A_FP32) {
            const float* A = (const float*)Ap;
#pragma unroll
            for (int i = 0; i < 8; i++) {
                int idx = tid + i * 256;          // 0..2047 float4 chunks
                int r = idx >> 4, c = idx & 15;
                int rg = row0 + r; if (rg >= nrows) rg = nrows - 1;
                float4 v = *(const float4*)(A + (size_t)rg * K + k0 + c * 4);
                half4v h = { (_Float16)v.x, (_Float16)v.y, (_Float16)v.z, (_Float16)v.w };
                *(half4v*)&Asm[r * LDK + c * 4] = h;
            }
        } else {
            const _Float16* A = (const _Float16*)Ap;
#pragma unroll
            for (int i = 0; i < 4; i++) {
                int idx = tid + i * 256;          // 0..1023 half8 chunks
                int r = idx >> 3, c = idx & 7;
                int rg = row0 + r; if (rg >= nrows) rg = nrows - 1;
                half8 v = *(const half8*)(A + (size_t)rg * K + k0 + c * 8);
                *(half8*)&Asm[r * LDK + c * 8] = v;
            }
        }
#pragma unroll
        for (int i = 0; i < 4; i++) {
            int idx = tid + i * 256;              // 0..1023 half8 chunks
            int r = idx >> 3, c = idx & 7;
            half8 v = *(const half8*)(Bt + (size_t)r * K + k0 + c * 8);
            *(half8*)&Bsm[r * LDK + c * 8] = v;
        }
        __syncthreads();
#pragma unroll
        for (int ks = 0; ks < 2; ks++) {
            half8 af[4], bf[4];
#pragma unroll
            for (int r = 0; r < 4; r++)
                af[r] = *(half8*)&Asm[(wy * 64 + r * 16 + m16) * LDK + ks * 32 + quad * 8];
#pragma unroll
            for (int c = 0; c < 4; c++)
                bf[c] = *(half8*)&Bsm[(wx * 64 + c * 16 + m16) * LDK + ks * 32 + quad * 8];
#pragma unroll
            for (int r = 0; r < 4; r++)
#pragma unroll
                for (int c = 0; c < 4; c++)
                    acc[r][c] = __builtin_amdgcn_mfma_f32_16x16x32_f16(af[r], bf[c], acc[r][c], 0, 0, 0);
        }
    }
#pragma unroll
    for (int r = 0; r < 4; r++) {
#pragma unroll
        for (int v = 0; v < 4; v++) {
            int m = wy * 64 + r * 16 + quad * 4 + v;
            int row = row0 + m;
            if (row < nrows) {
#pragma unroll
                for (int c = 0; c < 4; c++) {
                    int n = wx * 64 + c * 16 + m16;
                    float val = acc[r][c][v] + bv[c];
                    if (OUT_HALF) ((_Float16*)outp)[(size_t)row * HID + n] = (_Float16)val;
                    else          ((float*)outp)[(size_t)row * HID + n] = val;
                }
            }
        }
    }
}

// ------------------------- LayerNorm + ReLU (fp32 in, fp16 out) -------------------------

__global__ __launch_bounds__(256) void ln_relu_kernel(const float* __restrict__ x,
                                                      const float* __restrict__ g,
                                                      const float* __restrict__ b,
                                                      _Float16* __restrict__ a) {
    int row = (blockIdx.x * 256 + threadIdx.x) >> 6;
    int lane = threadIdx.x & 63;
    if (row >= N_NODES) return;
    float2 v = *(const float2*)(x + (size_t)row * HID + 2 * lane);
    float s = v.x + v.y;
#pragma unroll
    for (int off = 1; off < 64; off <<= 1) s += __shfl_xor(s, off);
    float mu = s * (1.0f / 128.0f);
    float d0 = v.x - mu, d1 = v.y - mu;
    float q = d0 * d0 + d1 * d1;
#pragma unroll
    for (int off = 1; off < 64; off <<= 1) q += __shfl_xor(q, off);
    float rstd = rsqrtf(q * (1.0f / 128.0f) + LN_EPS);
    float2 gg = *(const float2*)(g + 2 * lane);
    float2 bb = *(const float2*)(b + 2 * lane);
    float h0 = d0 * rstd * gg.x + bb.x;
    float h1 = d1 * rstd * gg.y + bb.y;
    h0 = h0 > 0.f ? h0 : 0.f;
    h1 = h1 > 0.f ? h1 : 0.f;
    half2v h = { (_Float16)h0, (_Float16)h1 };
    *(half2v*)(a + (size_t)row * HID + 2 * lane) = h;
}

// ------------------------- edge aggregation (fp16 gather, fp32 acc) -------------------------

__global__ __launch_bounds__(128) void edge_agg_kernel(const _Float16* __restrict__ a,
                                                       const int* __restrict__ edge_nbr,
                                                       const unsigned* __restrict__ offs,
                                                       const float* __restrict__ inv_ce,
                                                       _Float16* __restrict__ Ae) {
    __shared__ int nbrs[128];
    int m = blockIdx.x;
    int t = threadIdx.x;
    unsigned beg = offs[m], end = offs[m + 1];
    int deg = (int)(end - beg);
    float sum = 0.f;
    for (int j0 = 0; j0 < deg; j0 += 128) {
        __syncthreads();
        if (j0 + t < deg) nbrs[t] = edge_nbr[beg + j0 + t];
        __syncthreads();
        int lim = min(128, deg - j0);
        int k = 0;
        for (; k + 4 <= lim; k += 4) {
            int v0 = nbrs[k], v1 = nbrs[k + 1], v2 = nbrs[k + 2], v3 = nbrs[k + 3];
            float s0 = (float)a[(size_t)v0 * HID + t];
            float s1 = (float)a[(size_t)v1 * HID + t];
            float s2 = (float)a[(size_t)v2 * HID + t];
            float s3 = (float)a[(size_t)v3 * HID + t];
            sum += s0 + s1 + s2 + s3;
        }
        for (; k < lim; k++) sum += (float)a[(size_t)nbrs[k] * HID + t];
    }
    Ae[(size_t)m * HID + t] = (_Float16)(sum * inv_ce[m]);
}

// ------------------------- vertex aggregation + residual -------------------------

__global__ __launch_bounds__(256) void vert_agg_kernel(const _Float16* __restrict__ Xe,
                                                       const int* __restrict__ vert_nbr,
                                                       const unsigned* __restrict__ offs,
                                                       const float* __restrict__ inv_cv,
                                                       float* __restrict__ x) {
    int v = (blockIdx.x * 256 + threadIdx.x) >> 6;
    int lane = threadIdx.x & 63;
    if (v >= N_NODES) return;
    unsigned beg = offs[v], end = offs[v + 1];
    float s0 = 0.f, s1 = 0.f;
    for (unsigned j = beg; j < end; j++) {
        int e = vert_nbr[j];
        half2v h = *(const half2v*)(Xe + (size_t)e * HID + 2 * lane);
        s0 += (float)h[0];
        s1 += (float)h[1];
    }
    float ic = inv_cv[v];
    float y0 = s0 * ic, y1 = s1 * ic;
    y0 = y0 > 0.f ? y0 : 0.f;
    y1 = y1 > 0.f ? y1 : 0.f;
    float2* xp = (float2*)(x + (size_t)v * HID + 2 * lane);
    float2 old = *xp;
    old.x += y0; old.y += y1;
    *xp = old;
}

// ------------------------- head: x @ W_out + b_out, log_softmax -------------------------

__global__ __launch_bounds__(256) void out_kernel(const float* __restrict__ x,
                                                  const float* __restrict__ Wo,
                                                  const float* __restrict__ bo,
                                                  float* __restrict__ out) {
    __shared__ float Ws[128][16];
    __shared__ float rowbuf[16][132];
    __shared__ float bsm[16];
    int tid = threadIdx.x;
#pragma unroll
    for (int i = 0; i < 8; i++) {
        int idx = tid + i * 256;
        ((float*)Ws)[idx] = Wo[idx];
    }
    if (tid < 16) bsm[tid] = bo[tid];
    int row0 = blockIdx.x * 16;
    int w = tid >> 6, lane = tid & 63;
#pragma unroll
    for (int i = 0; i < 8; i++) {
        int idx = lane + i * 64;
        int r = idx >> 7, k = idx & 127;
        int row = row0 + w * 4 + r;
        rowbuf[w * 4 + r][k] = (row < N_NODES) ? x[(size_t)row * HID + k] : 0.f;
    }
    __syncthreads();
    int r = lane >> 4, c = lane & 15;
    int row = row0 + w * 4 + r;
    float acc = bsm[c];
#pragma unroll
    for (int k = 0; k < 128; k++) acc += rowbuf[w * 4 + r][k] * Ws[k][c];
    float mx = acc;
#pragma unroll
    for (int off = 1; off < 16; off <<= 1) mx = fmaxf(mx, __shfl_xor(mx, off));
    float e = expf(acc - mx);
    float s = e;
#pragma unroll
    for (int off = 1; off < 16; off <<= 1) s += __shfl_xor(s, off);
    float val = acc - mx - logf(s);
    if (row < N_NODES) out[(size_t)row * OUT_C + c] = val;
}

// ------------------------- launch -------------------------

extern "C" void kernel_launch(void* const* d_in, const int* in_sizes, int n_in,
                              void* d_out, int out_size, void* d_ws, size_t ws_size,
                              hipStream_t stream) {
    const float* X     = (const float*)d_in[0];
    const int*   v_idx = (const int*)d_in[1];
    const int*   e_idx = (const int*)d_in[2];
    const float* W_enc = (const float*)d_in[3];
    const float* b_enc = (const float*)d_in[4];
    const float* ln_g  = (const float*)d_in[5];
    const float* ln_b  = (const float*)d_in[6];
    const float* Wt    = (const float*)d_in[7];
    const float* bt    = (const float*)d_in[8];
    const float* W_out = (const float*)d_in[9];
    const float* b_out = (const float*)d_in[10];
    float* out = (float*)d_out;

    char* ws = (char*)d_ws;
    auto alloc = [&](size_t bytes) -> void* {
        void* p = (void*)ws;
        ws += (bytes + 255) & ~(size_t)255;
        return p;
    };
    float*    x       = (float*)alloc((size_t)N_NODES * HID * 4);
    _Float16* a_h     = (_Float16*)alloc((size_t)N_NODES * HID * 2);
    _Float16* Ae_h    = (_Float16*)alloc((size_t)M_EDGES * HID * 2);
    _Float16* Xe_h    = (_Float16*)alloc((size_t)M_EDGES * HID * 2);
    _Float16* WencT_h = (_Float16*)alloc((size_t)CIN * HID * 2);
    _Float16* WtT_h   = (_Float16*)alloc((size_t)NLAYERS * HID * HID * 2);
    int* edge_nbr = (int*)alloc((size_t)P_PAIRS * 4);
    int* vert_nbr = (int*)alloc((size_t)P_PAIRS * 4);
    unsigned* cnt_e = (unsigned*)alloc((size_t)(M_EDGES + N_NODES) * 4);
    unsigned* cnt_v = cnt_e + M_EDGES;
    unsigned* offs_e = (unsigned*)alloc((size_t)(M_EDGES + 1) * 4);
    unsigned* offs_v = (unsigned*)alloc((size_t)(N_NODES + 1) * 4);
    unsigned* cur_e  = (unsigned*)alloc((size_t)M_EDGES * 4);
    unsigned* cur_v  = (unsigned*)alloc((size_t)N_NODES * 4);
    float* inv_ce = (float*)alloc((size_t)M_EDGES * 4);
    float* inv_cv = (float*)alloc((size_t)N_NODES * 4);

    // CSR build
    hipMemsetAsync(cnt_e, 0, (size_t)(M_EDGES + N_NODES) * 4, stream);
    hist_kernel<<<(P_PAIRS + 255) / 256, 256, 0, stream>>>(v_idx, e_idx, cnt_v, cnt_e);
    scan_kernel<<<1, 1024, 0, stream>>>(cnt_e, M_EDGES, offs_e, cur_e, inv_ce);
    scan_kernel<<<1, 1024, 0, stream>>>(cnt_v, N_NODES, offs_v, cur_v, inv_cv);
    fill_kernel<<<(P_PAIRS + 255) / 256, 256, 0, stream>>>(v_idx, e_idx, cur_v, cur_e,
                                                           vert_nbr, edge_nbr);

    // weight conversion (fp32 -> fp16, k-contiguous transpose)
    {
        dim3 g1((CIN * HID + 255) / 256, 1);
        convert_wT_kernel<<<g1, 256, 0, stream>>>(W_enc, WencT_h, CIN);
        dim3 g2((HID * HID + 255) / 256, NLAYERS);
        convert_wT_kernel<<<g2, 256, 0, stream>>>(Wt, WtT_h, HID);
    }

    // encoder: x = X @ W_enc + b_enc   (fp32 A, fp32 out)
    mfma_gemm_kernel<true, false><<<(N_NODES + 127) / 128, 256, 0, stream>>>(
        (const void*)X, WencT_h, b_enc, (void*)x, N_NODES, CIN);

    // 16 layers
    for (int l = 0; l < NLAYERS; l++) {
        ln_relu_kernel<<<(N_NODES * 64 + 255) / 256, 256, 0, stream>>>(
            x, ln_g + l * HID, ln_b + l * HID, a_h);
        edge_agg_kernel<<<M_EDGES, 128, 0, stream>>>(a_h, edge_nbr, offs_e, inv_ce, Ae_h);
        mfma_gemm_kernel<false, true><<<(M_EDGES + 127) / 128, 256, 0, stream>>>(
            (const void*)Ae_h, WtT_h + (size_t)l * HID * HID, bt + l * HID,
            (void*)Xe_h, M_EDGES, HID);
        vert_agg_kernel<<<(N_NODES * 64 + 255) / 256, 256, 0, stream>>>(
            Xe_h, vert_nbr, offs_v, inv_cv, x);
    }

    // head
    out_kernel<<<(N_NODES + 15) / 16, 256, 0, stream>>>(x, W_out, b_out, out);
}

// Round 3
// 3234.714 us; speedup vs baseline: 1.9883x; 1.4187x over previous
//
#include <hip/hip_runtime.h>
#include <cstdint>
#include <cstddef>

#define N_NODES 100000
#define M_EDGES 20000
#define P_PAIRS 1600000
#define CIN 768
#define HID 128
#define OUT_C 16
#define NLAYERS 16
#define LN_EPS 1e-5f

using half8  = __attribute__((ext_vector_type(8))) _Float16;
using half4v = __attribute__((ext_vector_type(4))) _Float16;
using half2v = __attribute__((ext_vector_type(2))) _Float16;
using f32x4  = __attribute__((ext_vector_type(4))) float;

// ------------------------- CSR build -------------------------

__global__ void hist_kernel(const int* __restrict__ v_idx, const int* __restrict__ e_idx,
                            unsigned* __restrict__ cnt_v, unsigned* __restrict__ cnt_e) {
    int p = blockIdx.x * 256 + threadIdx.x;
    if (p < P_PAIRS) {
        atomicAdd(&cnt_v[v_idx[p]], 1u);
        atomicAdd(&cnt_e[e_idx[p]], 1u);
    }
}

// ---- parallel scan: 3 phases ----
#define SCAN_EPT 16
#define SCAN_CHUNK 4096   // 256 threads * 16

__global__ void scan_block_sums(const unsigned* __restrict__ cnt, int n,
                                unsigned* __restrict__ bsum) {
    __shared__ unsigned ws[4];
    int t = threadIdx.x;
    int base = blockIdx.x * SCAN_CHUNK + t * SCAN_EPT;
    unsigned s = 0;
#pragma unroll
    for (int i = 0; i < SCAN_EPT; i++) {
        int idx = base + i;
        if (idx < n) s += cnt[idx];
    }
#pragma unroll
    for (int off = 1; off < 64; off <<= 1) s += __shfl_xor(s, off);
    int lane = t & 63, w = t >> 6;
    if (lane == 0) ws[w] = s;
    __syncthreads();
    if (t == 0) bsum[blockIdx.x] = ws[0] + ws[1] + ws[2] + ws[3];
}

// single wave; B <= 64
__global__ void scan_tops(const unsigned* __restrict__ bsum, int B,
                          unsigned* __restrict__ bbase, unsigned* __restrict__ total_out) {
    int t = threadIdx.x;
    unsigned v = (t < B) ? bsum[t] : 0u;
    unsigned s = v;
#pragma unroll
    for (int off = 1; off < 64; off <<= 1) {
        unsigned u = __shfl_up(s, off);
        if (t >= off) s += u;
    }
    if (t < B) bbase[t] = s - v;
    if (t == 63) *total_out = s;
}

__global__ void scan_final(const unsigned* __restrict__ cnt, int n,
                           const unsigned* __restrict__ bbase,
                           unsigned* __restrict__ offs, unsigned* __restrict__ cur,
                           float* __restrict__ inv) {
    __shared__ unsigned wtot[4];
    int t = threadIdx.x;
    int lane = t & 63, w = t >> 6;
    int base = blockIdx.x * SCAN_CHUNK + t * SCAN_EPT;
    unsigned vals[SCAN_EPT];
    unsigned tsum = 0;
#pragma unroll
    for (int i = 0; i < SCAN_EPT; i++) {
        int idx = base + i;
        unsigned v = (idx < n) ? cnt[idx] : 0u;
        vals[i] = v;
        tsum += v;
    }
    unsigned s = tsum;
#pragma unroll
    for (int off = 1; off < 64; off <<= 1) {
        unsigned u = __shfl_up(s, off);
        if (lane >= off) s += u;
    }
    unsigned texcl = s - tsum;
    if (lane == 63) wtot[w] = s;
    __syncthreads();
    unsigned wbase = 0;
    for (int i = 0; i < w; i++) wbase += wtot[i];
    unsigned run = bbase[blockIdx.x] + wbase + texcl;
#pragma unroll
    for (int i = 0; i < SCAN_EPT; i++) {
        int idx = base + i;
        if (idx < n) {
            offs[idx] = run;
            cur[idx] = run;
            unsigned c = vals[i];
            inv[idx] = 1.0f / (float)(c > 1u ? c : 1u);
            run += c;
        }
    }
}

// ---- fills: split so each kernel's scatter set fits (close to) one XCD L2 ----

__global__ void fill_v_kernel(const int* __restrict__ v_idx, const int* __restrict__ e_idx,
                              unsigned* __restrict__ cur_v, unsigned short* __restrict__ vert_nbr) {
    int p = blockIdx.x * 256 + threadIdx.x;
    if (p < P_PAIRS) {
        unsigned s = atomicAdd(&cur_v[v_idx[p]], 1u);
        vert_nbr[s] = (unsigned short)e_idx[p];   // e < 20000 fits u16
    }
}

__global__ void fill_e_kernel(const int* __restrict__ v_idx, const int* __restrict__ e_idx,
                              unsigned* __restrict__ cur_e, int* __restrict__ edge_nbr) {
    int p = blockIdx.x * 256 + threadIdx.x;
    if (p < P_PAIRS) {
        unsigned s = atomicAdd(&cur_e[e_idx[p]], 1u);
        edge_nbr[s] = v_idx[p];
    }
}

// ------------------------- weight transpose+convert -------------------------

__global__ void convert_wT_kernel(const float* __restrict__ W, _Float16* __restrict__ WT,
                                  int K) {
    const float* src = W + (size_t)blockIdx.y * K * 128;
    _Float16* dst = WT + (size_t)blockIdx.y * K * 128;
    int idx = blockIdx.x * 256 + threadIdx.x;
    if (idx < K * 128) {
        int k = idx >> 7, n = idx & 127;
        dst[(size_t)n * K + k] = (_Float16)src[idx];
    }
}

// ------------------------- MFMA GEMM -------------------------

#define BK  64
#define LDK 72

template<bool A_FP32, bool OUT_HALF>
__global__ __launch_bounds__(256) void mfma_gemm_kernel(
    const void* __restrict__ Ap, const _Float16* __restrict__ Bt,
    const float* __restrict__ bias, void* __restrict__ outp,
    int nrows, int K) {
    __shared__ _Float16 Asm[128 * LDK];
    __shared__ _Float16 Bsm[128 * LDK];
    int tid = threadIdx.x;
    int row0 = blockIdx.x * 128;
    int lane = tid & 63, wave = tid >> 6;
    int wy = wave >> 1, wx = wave & 1;
    int m16 = lane & 15, quad = lane >> 4;

    f32x4 acc[4][4];
#pragma unroll
    for (int r = 0; r < 4; r++)
#pragma unroll
        for (int c = 0; c < 4; c++) acc[r][c] = (f32x4)0.f;

    float bv[4];
#pragma unroll
    for (int c = 0; c < 4; c++) bv[c] = bias[wx * 64 + c * 16 + m16];

    for (int k0 = 0; k0 < K; k0 += BK) {
        __syncthreads();
        if (A_FP32) {
            const float* A = (const float*)Ap;
#pragma unroll
            for (int i = 0; i < 8; i++) {
                int idx = tid + i * 256;
                int r = idx >> 4, c = idx & 15;
                int rg = row0 + r; if (rg >= nrows) rg = nrows - 1;
                float4 v = *(const float4*)(A + (size_t)rg * K + k0 + c * 4);
                half4v h = { (_Float16)v.x, (_Float16)v.y, (_Float16)v.z, (_Float16)v.w };
                *(half4v*)&Asm[r * LDK + c * 4] = h;
            }
        } else {
            const _Float16* A = (const _Float16*)Ap;
#pragma unroll
            for (int i = 0; i < 4; i++) {
                int idx = tid + i * 256;
                int r = idx >> 3, c = idx & 7;
                int rg = row0 + r; if (rg >= nrows) rg = nrows - 1;
                half8 v = *(const half8*)(A + (size_t)rg * K + k0 + c * 8);
                *(half8*)&Asm[r * LDK + c * 8] = v;
            }
        }
#pragma unroll
        for (int i = 0; i < 4; i++) {
            int idx = tid + i * 256;
            int r = idx >> 3, c = idx & 7;
            half8 v = *(const half8*)(Bt + (size_t)r * K + k0 + c * 8);
            *(half8*)&Bsm[r * LDK + c * 8] = v;
        }
        __syncthreads();
#pragma unroll
        for (int ks = 0; ks < 2; ks++) {
            half8 af[4], bf[4];
#pragma unroll
            for (int r = 0; r < 4; r++)
                af[r] = *(half8*)&Asm[(wy * 64 + r * 16 + m16) * LDK + ks * 32 + quad * 8];
#pragma unroll
            for (int c = 0; c < 4; c++)
                bf[c] = *(half8*)&Bsm[(wx * 64 + c * 16 + m16) * LDK + ks * 32 + quad * 8];
#pragma unroll
            for (int r = 0; r < 4; r++)
#pragma unroll
                for (int c = 0; c < 4; c++)
                    acc[r][c] = __builtin_amdgcn_mfma_f32_16x16x32_f16(af[r], bf[c], acc[r][c], 0, 0, 0);
        }
    }
#pragma unroll
    for (int r = 0; r < 4; r++) {
#pragma unroll
        for (int v = 0; v < 4; v++) {
            int m = wy * 64 + r * 16 + quad * 4 + v;
            int row = row0 + m;
            if (row < nrows) {
#pragma unroll
                for (int c = 0; c < 4; c++) {
                    int n = wx * 64 + c * 16 + m16;
                    float val = acc[r][c][v] + bv[c];
                    if (OUT_HALF) ((_Float16*)outp)[(size_t)row * HID + n] = (_Float16)val;
                    else          ((float*)outp)[(size_t)row * HID + n] = val;
                }
            }
        }
    }
}

// ------------------------- LayerNorm + ReLU (layer 0 only) -------------------------

__global__ __launch_bounds__(256) void ln_relu_kernel(const float* __restrict__ x,
                                                      const float* __restrict__ g,
                                                      const float* __restrict__ b,
                                                      _Float16* __restrict__ a) {
    int row = (blockIdx.x * 256 + threadIdx.x) >> 6;
    int lane = threadIdx.x & 63;
    if (row >= N_NODES) return;
    float2 v = *(const float2*)(x + (size_t)row * HID + 2 * lane);
    float s = v.x + v.y;
#pragma unroll
    for (int off = 1; off < 64; off <<= 1) s += __shfl_xor(s, off);
    float mu = s * (1.0f / 128.0f);
    float d0 = v.x - mu, d1 = v.y - mu;
    float q = d0 * d0 + d1 * d1;
#pragma unroll
    for (int off = 1; off < 64; off <<= 1) q += __shfl_xor(q, off);
    float rstd = rsqrtf(q * (1.0f / 128.0f) + LN_EPS);
    float2 gg = *(const float2*)(g + 2 * lane);
    float2 bb = *(const float2*)(b + 2 * lane);
    float h0 = fmaxf(d0 * rstd * gg.x + bb.x, 0.f);
    float h1 = fmaxf(d1 * rstd * gg.y + bb.y, 0.f);
    half2v h = { (_Float16)h0, (_Float16)h1 };
    *(half2v*)(a + (size_t)row * HID + 2 * lane) = h;
}

// ------------------------- edge aggregation: one wave per edge -------------------------

__global__ __launch_bounds__(256) void edge_agg_kernel(const _Float16* __restrict__ a,
                                                       const int* __restrict__ edge_nbr,
                                                       const unsigned* __restrict__ offs,
                                                       const float* __restrict__ inv_ce,
                                                       _Float16* __restrict__ Ae) {
    int m = blockIdx.x * 4 + (threadIdx.x >> 6);
    int lane = threadIdx.x & 63;
    unsigned beg = offs[m], end = offs[m + 1];
    float s0 = 0.f, s1 = 0.f;
    unsigned j = beg;
    for (; j + 4 <= end; j += 4) {
        int v0 = edge_nbr[j], v1 = edge_nbr[j + 1], v2 = edge_nbr[j + 2], v3 = edge_nbr[j + 3];
        half2v h0 = *(const half2v*)(a + (size_t)v0 * HID + 2 * lane);
        half2v h1 = *(const half2v*)(a + (size_t)v1 * HID + 2 * lane);
        half2v h2 = *(const half2v*)(a + (size_t)v2 * HID + 2 * lane);
        half2v h3 = *(const half2v*)(a + (size_t)v3 * HID + 2 * lane);
        s0 += (float)h0[0] + (float)h1[0] + (float)h2[0] + (float)h3[0];
        s1 += (float)h0[1] + (float)h1[1] + (float)h2[1] + (float)h3[1];
    }
    for (; j < end; j++) {
        int v = edge_nbr[j];
        half2v h = *(const half2v*)(a + (size_t)v * HID + 2 * lane);
        s0 += (float)h[0];
        s1 += (float)h[1];
    }
    float ic = inv_ce[m];
    half2v o = { (_Float16)(s0 * ic), (_Float16)(s1 * ic) };
    *(half2v*)(Ae + (size_t)m * HID + 2 * lane) = o;
}

// ------------------------- vertex aggregation + residual + fused next-layer LN -------------------------

__global__ __launch_bounds__(256) void vert_fused_kernel(
    const _Float16* __restrict__ Xe, const unsigned short* __restrict__ vert_nbr,
    const unsigned* __restrict__ offs, const float* __restrict__ inv_cv,
    float* __restrict__ x, const float* __restrict__ g, const float* __restrict__ b,
    _Float16* __restrict__ a, int do_ln) {
    int v = (blockIdx.x * 256 + threadIdx.x) >> 6;
    int lane = threadIdx.x & 63;
    unsigned beg = offs[v], end = offs[v + 1];
    float s0 = 0.f, s1 = 0.f;
    unsigned j = beg;
    for (; j + 4 <= end; j += 4) {
        int e0 = vert_nbr[j], e1 = vert_nbr[j + 1], e2 = vert_nbr[j + 2], e3 = vert_nbr[j + 3];
        half2v h0 = *(const half2v*)(Xe + (size_t)e0 * HID + 2 * lane);
        half2v h1 = *(const half2v*)(Xe + (size_t)e1 * HID + 2 * lane);
        half2v h2 = *(const half2v*)(Xe + (size_t)e2 * HID + 2 * lane);
        half2v h3 = *(const half2v*)(Xe + (size_t)e3 * HID + 2 * lane);
        s0 += (float)h0[0] + (float)h1[0] + (float)h2[0] + (float)h3[0];
        s1 += (float)h0[1] + (float)h1[1] + (float)h2[1] + (float)h3[1];
    }
    for (; j < end; j++) {
        int e = vert_nbr[j];
        half2v h = *(const half2v*)(Xe + (size_t)e * HID + 2 * lane);
        s0 += (float)h[0];
        s1 += (float)h[1];
    }
    float ic = inv_cv[v];
    float y0 = fmaxf(s0 * ic, 0.f), y1 = fmaxf(s1 * ic, 0.f);
    float2* xp = (float2*)(x + (size_t)v * HID + 2 * lane);
    float2 xv = *xp;
    xv.x += y0; xv.y += y1;
    *xp = xv;
    if (do_ln) {
        float s = xv.x + xv.y;
#pragma unroll
        for (int off = 1; off < 64; off <<= 1) s += __shfl_xor(s, off);
        float mu = s * (1.0f / 128.0f);
        float d0 = xv.x - mu, d1 = xv.y - mu;
        float q = d0 * d0 + d1 * d1;
#pragma unroll
        for (int off = 1; off < 64; off <<= 1) q += __shfl_xor(q, off);
        float rstd = rsqrtf(q * (1.0f / 128.0f) + LN_EPS);
        float2 gg = *(const float2*)(g + 2 * lane);
        float2 bb = *(const float2*)(b + 2 * lane);
        float h0 = fmaxf(d0 * rstd * gg.x + bb.x, 0.f);
        float h1 = fmaxf(d1 * rstd * gg.y + bb.y, 0.f);
        half2v h = { (_Float16)h0, (_Float16)h1 };
        *(half2v*)(a + (size_t)v * HID + 2 * lane) = h;
    }
}

// ------------------------- head: x @ W_out + b_out, log_softmax -------------------------

__global__ __launch_bounds__(256) void out_kernel(const float* __restrict__ x,
                                                  const float* __restrict__ Wo,
                                                  const float* __restrict__ bo,
                                                  float* __restrict__ out) {
    __shared__ float Ws[128][16];
    __shared__ float rowbuf[16][132];
    __shared__ float bsm[16];
    int tid = threadIdx.x;
#pragma unroll
    for (int i = 0; i < 8; i++) {
        int idx = tid + i * 256;
        ((float*)Ws)[idx] = Wo[idx];
    }
    if (tid < 16) bsm[tid] = bo[tid];
    int row0 = blockIdx.x * 16;
    int w = tid >> 6, lane = tid & 63;
#pragma unroll
    for (int i = 0; i < 8; i++) {
        int idx = lane + i * 64;
        int r = idx >> 7, k = idx & 127;
        int row = row0 + w * 4 + r;
        rowbuf[w * 4 + r][k] = (row < N_NODES) ? x[(size_t)row * HID + k] : 0.f;
    }
    __syncthreads();
    int r = lane >> 4, c = lane & 15;
    int row = row0 + w * 4 + r;
    float acc = bsm[c];
#pragma unroll
    for (int k = 0; k < 128; k++) acc += rowbuf[w * 4 + r][k] * Ws[k][c];
    float mx = acc;
#pragma unroll
    for (int off = 1; off < 16; off <<= 1) mx = fmaxf(mx, __shfl_xor(mx, off));
    float e = expf(acc - mx);
    float s = e;
#pragma unroll
    for (int off = 1; off < 16; off <<= 1) s += __shfl_xor(s, off);
    float val = acc - mx - logf(s);
    if (row < N_NODES) out[(size_t)row * OUT_C + c] = val;
}

// ------------------------- launch -------------------------

extern "C" void kernel_launch(void* const* d_in, const int* in_sizes, int n_in,
                              void* d_out, int out_size, void* d_ws, size_t ws_size,
                              hipStream_t stream) {
    const float* X     = (const float*)d_in[0];
    const int*   v_idx = (const int*)d_in[1];
    const int*   e_idx = (const int*)d_in[2];
    const float* W_enc = (const float*)d_in[3];
    const float* b_enc = (const float*)d_in[4];
    const float* ln_g  = (const float*)d_in[5];
    const float* ln_b  = (const float*)d_in[6];
    const float* Wt    = (const float*)d_in[7];
    const float* bt    = (const float*)d_in[8];
    const float* W_out = (const float*)d_in[9];
    const float* b_out = (const float*)d_in[10];
    float* out = (float*)d_out;

    char* ws = (char*)d_ws;
    auto alloc = [&](size_t bytes) -> void* {
        void* p = (void*)ws;
        ws += (bytes + 255) & ~(size_t)255;
        return p;
    };
    float*    x       = (float*)alloc((size_t)N_NODES * HID * 4);
    _Float16* a_h     = (_Float16*)alloc((size_t)N_NODES * HID * 2);
    _Float16* Ae_h    = (_Float16*)alloc((size_t)M_EDGES * HID * 2);
    _Float16* Xe_h    = (_Float16*)alloc((size_t)M_EDGES * HID * 2);
    _Float16* WencT_h = (_Float16*)alloc((size_t)CIN * HID * 2);
    _Float16* WtT_h   = (_Float16*)alloc((size_t)NLAYERS * HID * HID * 2);
    int* edge_nbr = (int*)alloc((size_t)P_PAIRS * 4);
    unsigned short* vert_nbr = (unsigned short*)alloc((size_t)P_PAIRS * 2);
    unsigned* cnt_e = (unsigned*)alloc((size_t)(M_EDGES + N_NODES) * 4);
    unsigned* cnt_v = cnt_e + M_EDGES;
    unsigned* offs_e = (unsigned*)alloc((size_t)(M_EDGES + 1) * 4);
    unsigned* offs_v = (unsigned*)alloc((size_t)(N_NODES + 1) * 4);
    unsigned* cur_e  = (unsigned*)alloc((size_t)M_EDGES * 4);
    unsigned* cur_v  = (unsigned*)alloc((size_t)N_NODES * 4);
    float* inv_ce = (float*)alloc((size_t)M_EDGES * 4);
    float* inv_cv = (float*)alloc((size_t)N_NODES * 4);
    unsigned* bsum_e = (unsigned*)alloc(64 * 4);
    unsigned* bbase_e = (unsigned*)alloc(64 * 4);
    unsigned* bsum_v = (unsigned*)alloc(64 * 4);
    unsigned* bbase_v = (unsigned*)alloc(64 * 4);

    const int BE = (M_EDGES + SCAN_CHUNK - 1) / SCAN_CHUNK;   // 5
    const int BV = (N_NODES + SCAN_CHUNK - 1) / SCAN_CHUNK;   // 25

    // CSR build
    hipMemsetAsync(cnt_e, 0, (size_t)(M_EDGES + N_NODES) * 4, stream);
    hist_kernel<<<(P_PAIRS + 255) / 256, 256, 0, stream>>>(v_idx, e_idx, cnt_v, cnt_e);
    scan_block_sums<<<BE, 256, 0, stream>>>(cnt_e, M_EDGES, bsum_e);
    scan_tops<<<1, 64, 0, stream>>>(bsum_e, BE, bbase_e, offs_e + M_EDGES);
    scan_final<<<BE, 256, 0, stream>>>(cnt_e, M_EDGES, bbase_e, offs_e, cur_e, inv_ce);
    scan_block_sums<<<BV, 256, 0, stream>>>(cnt_v, N_NODES, bsum_v);
    scan_tops<<<1, 64, 0, stream>>>(bsum_v, BV, bbase_v, offs_v + N_NODES);
    scan_final<<<BV, 256, 0, stream>>>(cnt_v, N_NODES, bbase_v, offs_v, cur_v, inv_cv);
    fill_v_kernel<<<(P_PAIRS + 255) / 256, 256, 0, stream>>>(v_idx, e_idx, cur_v, vert_nbr);
    fill_e_kernel<<<(P_PAIRS + 255) / 256, 256, 0, stream>>>(v_idx, e_idx, cur_e, edge_nbr);

    // weight conversion
    {
        dim3 g1((CIN * HID + 255) / 256, 1);
        convert_wT_kernel<<<g1, 256, 0, stream>>>(W_enc, WencT_h, CIN);
        dim3 g2((HID * HID + 255) / 256, NLAYERS);
        convert_wT_kernel<<<g2, 256, 0, stream>>>(Wt, WtT_h, HID);
    }

    // encoder: x = X @ W_enc + b_enc
    mfma_gemm_kernel<true, false><<<(N_NODES + 127) / 128, 256, 0, stream>>>(
        (const void*)X, WencT_h, b_enc, (void*)x, N_NODES, CIN);

    // layer-0 LN
    ln_relu_kernel<<<(N_NODES * 64 + 255) / 256, 256, 0, stream>>>(
        x, ln_g, ln_b, a_h);

    // 16 layers
    for (int l = 0; l < NLAYERS; l++) {
        edge_agg_kernel<<<M_EDGES / 4, 256, 0, stream>>>(a_h, edge_nbr, offs_e, inv_ce, Ae_h);
        mfma_gemm_kernel<false, true><<<(M_EDGES + 127) / 128, 256, 0, stream>>>(
            (const void*)Ae_h, WtT_h + (size_t)l * HID * HID, bt + l * HID,
            (void*)Xe_h, M_EDGES, HID);
        int lnext = (l + 1 < NLAYERS) ? (l + 1) : (NLAYERS - 1);  // pointer kept valid; unused when do_ln=0
        vert_fused_kernel<<<N_NODES / 4, 256, 0, stream>>>(
            Xe_h, vert_nbr, offs_v, inv_cv, x,
            ln_g + (size_t)lnext * HID, ln_b + (size_t)lnext * HID, a_h,
            (l + 1 < NLAYERS) ? 1 : 0);
    }

    // head
    out_kernel<<<(N_NODES + 15) / 16, 256, 0, stream>>>(x, W_out, b_out, out);
}